// Round 1
// baseline (239.529 us; speedup 1.0000x reference)
//
#include <hip/hip_runtime.h>

// Wavelet low-pass analysis (stride-2) + synthesis (transposed conv) fused
// into two 18-tap polyphase FIR filters applied directly to the input:
//   even p: ya[p] = sum_d We[d] * sig_m[p - 8 + d]
//   odd  p: ya[p] = sum_d Wo[d] * sig_m[p - 9 + d]
// sig_m = symmetric extension of the 524288-long flattened per-batch signal.
//
// v2: LDS staging removed. Reuse between adjacent 20-float windows is only a
// 16-float halo -> L1 absorbs the 5x read amplification (671 MB through L1
// ~= 24 B/cyc/CU << 64 B/clk). This deletes the ds_write/ds_read round trip
// and the full vmcnt(0)+lgkmcnt(0) barrier drain per tile. Persistent
// grid-stride blocks (2048 x 256, 16 quads/thread) amortize setup and let the
// compiler overlap next-iteration loads with the FMA block. Nontemporal
// stores keep the write-once output stream from thrashing L2.

#define L_SIG 524288            // flattened per-batch length (128*4096) = 2^19
#define QPB   (L_SIG / 4)       // float4 quads per batch = 131072 = 2^17
#define NBLOCKS 2048
#define NTHREADS (NBLOCKS * 256)

typedef float f4 __attribute__((ext_vector_type(4)));

constexpr float RL[10] = {
    0.160102397974125f,   0.6038292697974729f,  0.7243085284385744f,
    0.13842814590110342f, -0.24229488706619015f, -0.03224486958502952f,
    0.07757149384006515f, -0.006241490213011705f, -0.012580751999015526f,
    0.003335725285001549f};

struct Coef { float we[18]; float wo[18]; };

constexpr Coef make_coef() {
    Coef c{};
    for (int d = 0; d < 18; ++d) {
        float se = 0.f, so = 0.f;
        for (int j = 0; j < 5; ++j) {
            int i = d - 2 * j;               // REC_LO tap index
            if (i >= 0 && i < 10) {
                se += RL[8 - 2 * j] * RL[i]; // DEC_LO[2j+1] = RL[8-2j]
                so += RL[9 - 2 * j] * RL[i]; // DEC_LO[2j]   = RL[9-2j]
            }
        }
        c.we[d] = se;
        c.wo[d] = so;
    }
    return c;
}

constexpr Coef CF = make_coef();

__global__ __launch_bounds__(256)
void wavelet_fused_kernel(const float* __restrict__ x, float* __restrict__ out,
                          int nquads) {
    const int gid = blockIdx.x * 256 + threadIdx.x;

    for (int idx = gid; idx < nquads; idx += NTHREADS) {
        const int    b  = idx >> 17;              // batch (QPB = 2^17)
        const int    q  = (idx & (QPB - 1)) << 2; // output base within batch
        const size_t bo = (size_t)b << 19;        // b * L_SIG
        const float* xb = x + bo;
        float*       ob = out + bo;

        const int w0 = q - 8;                     // lowest input index needed
        float v[20];

        if (w0 >= 0 && w0 + 20 <= L_SIG) {
            // Interior fast path: 5 dense float4 loads, 16B-aligned (w0 % 4 == 0).
            const f4* src = (const f4*)(xb + w0);
#pragma unroll
            for (int r = 0; r < 5; ++r) {
                f4 f = src[r];
                v[4 * r + 0] = f[0];
                v[4 * r + 1] = f[1];
                v[4 * r + 2] = f[2];
                v[4 * r + 3] = f[3];
            }
        } else {
            // Symmetric-mirror slow path: only 4 threads per batch land here.
#pragma unroll
            for (int t = 0; t < 20; ++t) {
                int k  = w0 + t;
                int km = (k < 0) ? (-1 - k) : ((k >= L_SIG) ? (2 * L_SIG - 1 - k) : k);
                v[t] = xb[km];
            }
        }

        // 4 consecutive outputs q..q+3 (even, odd, even, odd).
        float o0 = 0.f, o1 = 0.f, o2 = 0.f, o3 = 0.f;
#pragma unroll
        for (int d = 0; d < 18; ++d) {
            o0 += CF.we[d] * v[d];       // even output at q   : x[q-8+d]
            o1 += CF.wo[d] * v[d];       // odd  output at q+1 : x[(q+1)-9+d]
            o2 += CF.we[d] * v[d + 2];   // even output at q+2
            o3 += CF.wo[d] * v[d + 2];   // odd  output at q+3
        }

        f4 o = {o0, o1, o2, o3};
        __builtin_nontemporal_store(o, (f4*)(ob + q));
    }
}

extern "C" void kernel_launch(void* const* d_in, const int* in_sizes, int n_in,
                              void* d_out, int out_size, void* d_ws, size_t ws_size,
                              hipStream_t stream) {
    const float* x = (const float*)d_in[0];
    float* out     = (float*)d_out;
    const int nquads = in_sizes[0] >> 2;   // 8,388,608 total float4 outputs
    wavelet_fused_kernel<<<NBLOCKS, 256, 0, stream>>>(x, out, nquads);
}

// Round 2
// 228.349 us; speedup vs baseline: 1.0490x; 1.0490x over previous
//
#include <hip/hip_runtime.h>
#include <stdint.h>

// Wavelet low-pass analysis (stride-2) + synthesis (transposed conv) fused
// into two 18-tap polyphase FIR filters applied directly to the input:
//   even p: ya[p] = sum_d We[d] * sig_m[p - 8 + d]
//   odd  p: ya[p] = sum_d Wo[d] * sig_m[p - 9 + d]
// sig_m = symmetric extension of the 524288-long flattened per-batch signal.
//
// v3: back to dense-read + LDS-redistribute (v2's no-LDS variant was
// latency-bound at 29% HBM: 5x overlapping loads + full vmcnt(0) drain per
// grid-stride iteration). Changes vs the 220us v1:
//  - staging via __builtin_amdgcn_global_load_lds width=16 (no VGPR round
//    trip, no ds_write, 2 staging insts/thread instead of ~6+addr VALU)
//  - TILE 2048 with 2 output-quads/thread (strided 1024 so stores stay
//    1KB-coalesced and ds_read windows keep the conflict-free 16B lane
//    stride) -> half the blocks/barrier-drains per output byte.

#define L_SIG 524288            // flattened per-batch length (128*4096) = 2^19
#define TILE  2048
#define HALO  16                // only +-9 needed; 16 keeps float4 alignment
#define SMEM_N (TILE + 2 * HALO) // 2080 floats = 8320 B

typedef float f4 __attribute__((ext_vector_type(4)));

typedef __attribute__((address_space(3))) uint32_t lds_u32_t;
typedef const __attribute__((address_space(1))) uint32_t glb_u32_t;

// Async global->LDS DMA, 16 B per lane. LDS dest is wave-uniform base +
// lane*16 (m104) -- our lane-linear layout matches exactly.
__device__ __forceinline__ void stage16(const float* g, float* l) {
    __builtin_amdgcn_global_load_lds((glb_u32_t*)g, (lds_u32_t*)l, 16, 0, 0);
}

constexpr float RL[10] = {
    0.160102397974125f,   0.6038292697974729f,  0.7243085284385744f,
    0.13842814590110342f, -0.24229488706619015f, -0.03224486958502952f,
    0.07757149384006515f, -0.006241490213011705f, -0.012580751999015526f,
    0.003335725285001549f};

struct Coef { float we[18]; float wo[18]; };

constexpr Coef make_coef() {
    Coef c{};
    for (int d = 0; d < 18; ++d) {
        float se = 0.f, so = 0.f;
        for (int j = 0; j < 5; ++j) {
            int i = d - 2 * j;               // REC_LO tap index
            if (i >= 0 && i < 10) {
                se += RL[8 - 2 * j] * RL[i]; // DEC_LO[2j+1] = RL[8-2j]
                so += RL[9 - 2 * j] * RL[i]; // DEC_LO[2j]   = RL[9-2j]
            }
        }
        c.we[d] = se;
        c.wo[d] = so;
    }
    return c;
}

constexpr Coef CF = make_coef();

__global__ __launch_bounds__(256)
void wavelet_fused_kernel(const float* __restrict__ x, float* __restrict__ out) {
    __shared__ float s[SMEM_N];

    const int batch = blockIdx.y;
    const int p0    = blockIdx.x * TILE;
    const float* xb = x   + (size_t)batch * L_SIG;
    float*       ob = out + (size_t)batch * L_SIG;
    const int t = threadIdx.x;

    const bool edge = (blockIdx.x == 0) || (blockIdx.x == gridDim.x - 1);

    if (edge) {
        // Scalar mirror staging (2 blocks/batch = 128 of 16384 blocks).
        // global_load_lds can't express the element-reversed mirror.
        for (int i = t; i < SMEM_N; i += 256) {
            int k  = p0 - HALO + i;
            int km = (k < 0) ? (-1 - k) : ((k >= L_SIG) ? (2 * L_SIG - 1 - k) : k);
            s[i] = xb[km];
        }
    } else {
        // Interior: 2080 floats staged by 2 full-width DMA calls + 8-lane tail.
        const float* src = xb + p0 - HALO;   // 16B-aligned (p0 % 2048 == 0)
        stage16(src + 4 * t,        s + 4 * t);
        stage16(src + 1024 + 4 * t, s + 1024 + 4 * t);
        if (t < 8)
            stage16(src + 2048 + 4 * t, s + 2048 + 4 * t);
    }
    __syncthreads();   // barrier drain waits vmcnt(0): DMA complete

    // Two output quads per thread, 1024 apart (stores stay 1KB-coalesced,
    // ds_read windows keep the 16B lane stride: 0 bank conflicts measured).
#pragma unroll
    for (int h = 0; h < 2; ++h) {
        const int q = 4 * t + 1024 * h;      // local output index

        float v[20];
        const f4* sp = (const f4*)(s + q + 8);  // = x[p0 + q - 8 ...]
#pragma unroll
        for (int r = 0; r < 5; ++r) {
            f4 f = sp[r];
            v[4 * r + 0] = f[0];
            v[4 * r + 1] = f[1];
            v[4 * r + 2] = f[2];
            v[4 * r + 3] = f[3];
        }

        float o0 = 0.f, o1 = 0.f, o2 = 0.f, o3 = 0.f;
#pragma unroll
        for (int d = 0; d < 18; ++d) {
            o0 += CF.we[d] * v[d];       // even output at q   : x[q-8+d]
            o1 += CF.wo[d] * v[d];       // odd  output at q+1 : x[(q+1)-9+d]
            o2 += CF.we[d] * v[d + 2];   // even output at q+2
            o3 += CF.wo[d] * v[d + 2];   // odd  output at q+3
        }

        f4 o = {o0, o1, o2, o3};
        __builtin_nontemporal_store(o, (f4*)(ob + p0 + q));
    }
}

extern "C" void kernel_launch(void* const* d_in, const int* in_sizes, int n_in,
                              void* d_out, int out_size, void* d_ws, size_t ws_size,
                              hipStream_t stream) {
    const float* x = (const float*)d_in[0];
    float* out     = (float*)d_out;

    const int B = in_sizes[0] / L_SIG;            // 64
    dim3 grid(L_SIG / TILE, B);                   // (256, 64)
    wavelet_fused_kernel<<<grid, 256, 0, stream>>>(x, out);
}